// Round 4
// baseline (1214.516 us; speedup 1.0000x reference)
//
#include <hip/hip_runtime.h>
#include <math.h>

// B=64, T=1000, S=96, A=32, INP=128, H=256. All I/O fp32.
// d_ws: pre fp16 [2][64000][256] = 65.536 MB, then h fp16 [2][64000][256] = 65.536 MB.

typedef _Float16 half2_t __attribute__((ext_vector_type(2)));

__device__ __forceinline__ float fdot2(half2_t a, half2_t b, float c) {
#if __has_builtin(__builtin_amdgcn_fdot2)
    return __builtin_amdgcn_fdot2(a, b, c, false);   // v_dot2_f32_f16
#else
    return c + (float)a[0] * (float)b[0] + (float)a[1] * (float)b[1];
#endif
}

// ---------------------------------------------------------------------------
// Kernel 1: feed-forward. Block = 64 rows. Thread = column PAIR (2 cols) x
// 32 rows -> each broadcast LDS row-read feeds 2 columns (2x fewer LDS instrs).
// Phase C (K=256) runs as two K=128 halves (weights fit VGPRs), fp32 partials
// staged in LDS between halves.
// ---------------------------------------------------------------------------
__global__ __launch_bounds__(256, 1)
void ff_kernel(const float* __restrict__ state,
               const float* __restrict__ action,
               const float* __restrict__ fc11_w, const float* __restrict__ fc11_b,
               const float* __restrict__ W_ih1,
               const float* __restrict__ b_hh1, const float* __restrict__ b_ih1,
               const float* __restrict__ fc21_w, const float* __restrict__ fc21_b,
               const float* __restrict__ W_ih2,
               const float* __restrict__ b_hh2, const float* __restrict__ b_ih2,
               _Float16* __restrict__ pre_out)
{
    __shared__ half2_t Xsh[64 * 64];      // 16 KB: 64 rows x 128 cols fp16
    __shared__ _Float16 X1h[64 * 256];    // 32 KB
    __shared__ float2  partC[64 * 128];   // 64 KB: phase-C K-half partials

    const int tile = blockIdx.x % 1000;
    const int br   = blockIdx.x / 1000;
    const float* Wa = br ? fc21_w : fc11_w;
    const float* ba = br ? fc21_b : fc11_b;
    const float* Wi = br ? W_ih2 : W_ih1;
    const float* bh = br ? b_hh2 : b_hh1;
    const float* bi = br ? b_ih2 : b_ih1;

    const int tid  = threadIdx.x;
    const int row0 = tile * 64;

    // stage X = concat(state, action) as half2 pairs
    const float2* st2 = (const float2*)(state + (size_t)row0 * 96);
    for (int p = tid; p < 64 * 48; p += 256) {
        int r = p / 48, i = p % 48;
        float2 v = st2[r * 48 + i];
        Xsh[r * 64 + i] = half2_t{(_Float16)v.x, (_Float16)v.y};
    }
    const float2* ac2 = (const float2*)(action + (size_t)row0 * 32);
    for (int p = tid; p < 64 * 16; p += 256) {
        int r = p / 16, i = p % 16;
        float2 v = ac2[r * 16 + i];
        Xsh[r * 64 + 48 + i] = half2_t{(_Float16)v.x, (_Float16)v.y};
    }
    __syncthreads();

    const int cp    = tid & 127;        // column pair index: cols (2cp, 2cp+1)
    const int c0    = 2 * cp;
    const int rbase = (tid >> 7) * 32;  // wave-uniform row half: 0 or 32

    // ---- phase B: X1 = relu(X @ Wa + ba), K=128, 2 cols/thread ----
    {
        half2_t w0[64], w1[64];
#pragma unroll
        for (int i = 0; i < 64; ++i) {
            const float* wp = Wa + (size_t)(2 * i) * 256 + c0;
            w0[i] = half2_t{(_Float16)wp[0], (_Float16)wp[256]};
            w1[i] = half2_t{(_Float16)wp[1], (_Float16)wp[257]};
        }
        const float bA = ba[c0], bB = ba[c0 + 1];

#pragma unroll 2
        for (int r = rbase; r < rbase + 32; ++r) {
            const float4* xr = (const float4*)&Xsh[r * 64];
            float s00 = bA, s01 = 0.f, s02 = 0.f, s03 = 0.f;
            float s10 = bB, s11 = 0.f, s12 = 0.f, s13 = 0.f;
#pragma unroll
            for (int k = 0; k < 16; ++k) {
                float4 v = xr[k];                     // 8 halves, wave-broadcast
                const half2_t* hh = (const half2_t*)&v;
                s00 = fdot2(hh[0], w0[4 * k + 0], s00);
                s01 = fdot2(hh[1], w0[4 * k + 1], s01);
                s02 = fdot2(hh[2], w0[4 * k + 2], s02);
                s03 = fdot2(hh[3], w0[4 * k + 3], s03);
                s10 = fdot2(hh[0], w1[4 * k + 0], s10);
                s11 = fdot2(hh[1], w1[4 * k + 1], s11);
                s12 = fdot2(hh[2], w1[4 * k + 2], s12);
                s13 = fdot2(hh[3], w1[4 * k + 3], s13);
            }
            float vA = (s00 + s01) + (s02 + s03); vA = vA > 0.f ? vA : 0.f;
            float vB = (s10 + s11) + (s12 + s13); vB = vB > 0.f ? vB : 0.f;
            ((half2_t*)X1h)[r * 128 + cp] = half2_t{(_Float16)vA, (_Float16)vB};
        }
    }
    __syncthreads();

    // ---- phase C: pre = X1 @ Wi + bias, K=256 as 2 halves of 128 ----
    _Float16* pre = pre_out + (size_t)br * 64000u * 256u;
    const float biasA = bh[c0] + bi[c0];
    const float biasB = bh[c0 + 1] + bi[c0 + 1];

    // K-half 0: accumulate into LDS partials
    {
        half2_t w0[64], w1[64];
#pragma unroll
        for (int i = 0; i < 64; ++i) {
            const float* wp = Wi + (size_t)(2 * i) * 256 + c0;
            w0[i] = half2_t{(_Float16)wp[0], (_Float16)wp[256]};
            w1[i] = half2_t{(_Float16)wp[1], (_Float16)wp[257]};
        }
#pragma unroll 2
        for (int r = 0; r < 32; ++r) {
            const int row = rbase + r;
            const float4* xr = (const float4*)&X1h[row * 256];
            float s00 = biasA, s01 = 0.f, s02 = 0.f, s03 = 0.f;
            float s10 = biasB, s11 = 0.f, s12 = 0.f, s13 = 0.f;
#pragma unroll
            for (int k = 0; k < 16; ++k) {
                float4 v = xr[k];
                const half2_t* hh = (const half2_t*)&v;
                s00 = fdot2(hh[0], w0[4 * k + 0], s00);
                s01 = fdot2(hh[1], w0[4 * k + 1], s01);
                s02 = fdot2(hh[2], w0[4 * k + 2], s02);
                s03 = fdot2(hh[3], w0[4 * k + 3], s03);
                s10 = fdot2(hh[0], w1[4 * k + 0], s10);
                s11 = fdot2(hh[1], w1[4 * k + 1], s11);
                s12 = fdot2(hh[2], w1[4 * k + 2], s12);
                s13 = fdot2(hh[3], w1[4 * k + 3], s13);
            }
            partC[row * 128 + cp] = float2{(s00 + s01) + (s02 + s03),
                                           (s10 + s11) + (s12 + s13)};
        }
    }
    // K-half 1: add partials, store pre (no barrier needed: each thread reads
    // only the partials it wrote itself)
    {
        half2_t w0[64], w1[64];
#pragma unroll
        for (int i = 0; i < 64; ++i) {
            const float* wp = Wi + (size_t)(128 + 2 * i) * 256 + c0;
            w0[i] = half2_t{(_Float16)wp[0], (_Float16)wp[256]};
            w1[i] = half2_t{(_Float16)wp[1], (_Float16)wp[257]};
        }
#pragma unroll 2
        for (int r = 0; r < 32; ++r) {
            const int row = rbase + r;
            const float4* xr = (const float4*)&X1h[row * 256 + 128];
            float s00 = 0.f, s01 = 0.f, s02 = 0.f, s03 = 0.f;
            float s10 = 0.f, s11 = 0.f, s12 = 0.f, s13 = 0.f;
#pragma unroll
            for (int k = 0; k < 16; ++k) {
                float4 v = xr[k];
                const half2_t* hh = (const half2_t*)&v;
                s00 = fdot2(hh[0], w0[4 * k + 0], s00);
                s01 = fdot2(hh[1], w0[4 * k + 1], s01);
                s02 = fdot2(hh[2], w0[4 * k + 2], s02);
                s03 = fdot2(hh[3], w0[4 * k + 3], s03);
                s10 = fdot2(hh[0], w1[4 * k + 0], s10);
                s11 = fdot2(hh[1], w1[4 * k + 1], s11);
                s12 = fdot2(hh[2], w1[4 * k + 2], s12);
                s13 = fdot2(hh[3], w1[4 * k + 3], s13);
            }
            float2 pp = partC[row * 128 + cp];
            float vA = pp.x + (s00 + s01) + (s02 + s03);
            float vB = pp.y + (s10 + s11) + (s12 + s13);
            ((half2_t*)(pre + (size_t)(row0 + row) * 256))[cp] =
                half2_t{(_Float16)vA, (_Float16)vB};
        }
    }
}

// ---------------------------------------------------------------------------
// Kernel 2: recurrence, split-K across 4 waves. Block = (branch,batch).
// Wave w owns k-slice [64w,64w+64); lane owns cols {4l..4l+3} (4x32 half2
// weights in VGPRs). Per step: 8 broadcast b128 h-reads + 1 b128 partial
// write + barrier + 4 b32 partial reads + sigmoid + h write. ONE barrier/step:
// wave w reduces exactly the h-slice it alone reads next step (same-wave
// lgkmcnt ordering); partial buffer ping-pongs by step parity.
// ---------------------------------------------------------------------------
__global__ __launch_bounds__(256, 1)
void rnn_kernel(const _Float16* __restrict__ pre_all,
                const float* __restrict__ hn,
                const float* __restrict__ W_hh1,
                const float* __restrict__ W_hh2,
                _Float16* __restrict__ h_out)
{
    __shared__ _Float16 hbuf[256];
    __shared__ float part[2][4][256];   // [parity][wave][col] = 8 KB

    const int wg = blockIdx.x;          // 0..127
    const int br = wg >> 6;
    const int b  = wg & 63;
    const float* Whh = br ? W_hh2 : W_hh1;
    const _Float16* pre = pre_all + ((size_t)br * 64000u + (size_t)b * 1000u) * 256u;
    _Float16* hg = h_out + ((size_t)br * 64000u + (size_t)b * 1000u) * 256u;

    const int t  = threadIdx.x;
    const int w  = t >> 6;              // wave id = k-slice
    const int l  = t & 63;
    const int k0 = w * 64;
    const int c0 = l * 4;               // 4 columns per lane

    // weights: cols {c0..c0+3} x k in [k0, k0+64), as half2 along k
    half2_t wh[4][32];
#pragma unroll
    for (int i = 0; i < 32; ++i) {
        const float* wp = Whh + (size_t)(k0 + 2 * i) * 256 + c0;
#pragma unroll
        for (int c = 0; c < 4; ++c)
            wh[c][i] = half2_t{(_Float16)wp[c], (_Float16)wp[256 + c]};
    }

    hbuf[t] = (_Float16)hn[b * 256 + t];
    __syncthreads();

    // 2-deep prefetch of pre[j=t]
    float pre_c = (float)pre[t];
    float pre_n = (float)pre[256 + t];

    for (int tt = 0; tt < 1000; ++tt) {
        // ---- compute: partial dot over own k-slice, 4 cols ----
        const float4* hb = (const float4*)&hbuf[k0];
        float s0 = 0.f, s1 = 0.f, s2 = 0.f, s3 = 0.f;
#pragma unroll
        for (int k = 0; k < 8; ++k) {
            float4 v = hb[k];                       // 8 halves, wave-broadcast
            const half2_t* hh = (const half2_t*)&v;
#pragma unroll
            for (int p = 0; p < 4; ++p) {
                s0 = fdot2(hh[p], wh[0][4 * k + p], s0);
                s1 = fdot2(hh[p], wh[1][4 * k + p], s1);
                s2 = fdot2(hh[p], wh[2][4 * k + p], s2);
                s3 = fdot2(hh[p], wh[3][4 * k + p], s3);
            }
        }
        const int pp = tt & 1;
        *(float4*)&part[pp][w][c0] = float4{s0, s1, s2, s3};
        __syncthreads();                            // publish partials

        // ---- reduce: output j = t (wave w handles its own next-step slice) ----
        const float z = ((part[pp][0][t] + part[pp][1][t]) +
                         (part[pp][2][t] + part[pp][3][t])) + pre_c;
        const float h = 1.0f / (1.0f + __expf(-z));
        const _Float16 h16 = (_Float16)h;
        hbuf[t] = h16;                              // same-wave consumer: no barrier
        hg[(size_t)tt * 256 + t] = h16;

        const int t2 = (tt + 2 < 1000) ? (tt + 2) : 999;
        pre_c = pre_n;
        pre_n = (float)pre[(size_t)t2 * 256 + t];
    }
}

// ---------------------------------------------------------------------------
// Kernel 3: q head. q[n] = h[n,:] . qw + qb. One thread per output.
// ---------------------------------------------------------------------------
__global__ __launch_bounds__(256, 2)
void q_kernel(const _Float16* __restrict__ h_all,
              const float* __restrict__ fc12_w, const float* __restrict__ fc12_b,
              const float* __restrict__ fc22_w, const float* __restrict__ fc22_b,
              float* __restrict__ out)
{
    const int n  = blockIdx.x * 256 + threadIdx.x;    // 500 blocks -> n < 128000
    const int br = (n >= 64000);                      // block-uniform
    const float* qwp = br ? fc22_w : fc12_w;
    const float  qb  = br ? fc22_b[0] : fc12_b[0];

    half2_t qw[128];
#pragma unroll
    for (int i = 0; i < 128; ++i)
        qw[i] = half2_t{(_Float16)qwp[2 * i], (_Float16)qwp[2 * i + 1]};

    const float4* hr = (const float4*)(h_all + (size_t)n * 256u);
    float s0 = qb, s1 = 0.f, s2 = 0.f, s3 = 0.f;
#pragma unroll
    for (int k = 0; k < 32; ++k) {
        float4 v = hr[k];
        const half2_t* hh = (const half2_t*)&v;
        s0 = fdot2(hh[0], qw[4 * k + 0], s0);
        s1 = fdot2(hh[1], qw[4 * k + 1], s1);
        s2 = fdot2(hh[2], qw[4 * k + 2], s2);
        s3 = fdot2(hh[3], qw[4 * k + 3], s3);
    }
    out[n] = (s0 + s1) + (s2 + s3);
}

// ---------------------------------------------------------------------------
extern "C" void kernel_launch(void* const* d_in, const int* in_sizes, int n_in,
                              void* d_out, int out_size, void* d_ws, size_t ws_size,
                              hipStream_t stream)
{
    const float* state  = (const float*)d_in[0];
    const float* action = (const float*)d_in[1];
    const float* hn     = (const float*)d_in[2];
    const float* fc11_w = (const float*)d_in[3];
    const float* fc11_b = (const float*)d_in[4];
    const float* W_hh1  = (const float*)d_in[5];
    const float* W_ih1  = (const float*)d_in[6];
    const float* b_hh1  = (const float*)d_in[7];
    const float* b_ih1  = (const float*)d_in[8];
    const float* fc12_w = (const float*)d_in[9];
    const float* fc12_b = (const float*)d_in[10];
    const float* fc21_w = (const float*)d_in[11];
    const float* fc21_b = (const float*)d_in[12];
    const float* W_hh2  = (const float*)d_in[13];
    const float* W_ih2  = (const float*)d_in[14];
    const float* b_hh2  = (const float*)d_in[15];
    const float* b_ih2  = (const float*)d_in[16];
    const float* fc22_w = (const float*)d_in[17];
    const float* fc22_b = (const float*)d_in[18];

    _Float16* pre = (_Float16*)d_ws;                // 65.536 MB
    _Float16* hbg = (_Float16*)d_ws + 32768000u;    // +65.536 MB

    ff_kernel<<<2000, 256, 0, stream>>>(state, action,
                                        fc11_w, fc11_b, W_ih1, b_hh1, b_ih1,
                                        fc21_w, fc21_b, W_ih2, b_hh2, b_ih2,
                                        pre);
    rnn_kernel<<<128, 256, 0, stream>>>(pre, hn, W_hh1, W_hh2, hbg);
    q_kernel<<<500, 256, 0, stream>>>(hbg, fc12_w, fc12_b, fc22_w, fc22_b,
                                      (float*)d_out);
}

// Round 5
// 1096.006 us; speedup vs baseline: 1.1081x; 1.1081x over previous
//
#include <hip/hip_runtime.h>
#include <math.h>

// B=64, T=1000, S=96, A=32, INP=128, H=256. All I/O fp32.
// d_ws: pre fp16 [2][64000][256] = 65.536 MB, then h fp16 [2][64000][256] = 65.536 MB.

typedef _Float16 half2_t __attribute__((ext_vector_type(2)));

__device__ __forceinline__ float fdot2(half2_t a, half2_t b, float c) {
#if __has_builtin(__builtin_amdgcn_fdot2)
    return __builtin_amdgcn_fdot2(a, b, c, false);   // v_dot2_f32_f16
#else
    return c + (float)a[0] * (float)b[0] + (float)a[1] * (float)b[1];
#endif
}

// Workgroup barrier WITHOUT the vmcnt(0) drain __syncthreads() inserts.
// Safe when inter-wave communication is LDS-only: lgkmcnt(0) retires all DS
// ops (making them visible in the physically-shared LDS), then raw s_barrier.
// In-flight global loads/stores stay in flight -> HBM latency off the
// critical path. "memory" clobber = compiler fence (no LDS op reordering).
__device__ __forceinline__ void barrier_lds() {
    __asm__ __volatile__("s_waitcnt lgkmcnt(0)" ::: "memory");
    __builtin_amdgcn_s_barrier();
}

// ---------------------------------------------------------------------------
// Kernel 1: feed-forward. Block = 64 rows of X. Thread = column PAIR x 32 rows
// (each broadcast LDS row-read feeds 2 columns). Phase C (K=256) = two K=128
// halves; inter-half partials in fp16 LDS that ALIASES the dead Xsh region.
// Total LDS 64 KB -> 2 blocks/CU.
// ---------------------------------------------------------------------------
__global__ __launch_bounds__(256, 2)
void ff_kernel(const float* __restrict__ state,
               const float* __restrict__ action,
               const float* __restrict__ fc11_w, const float* __restrict__ fc11_b,
               const float* __restrict__ W_ih1,
               const float* __restrict__ b_hh1, const float* __restrict__ b_ih1,
               const float* __restrict__ fc21_w, const float* __restrict__ fc21_b,
               const float* __restrict__ W_ih2,
               const float* __restrict__ b_hh2, const float* __restrict__ b_ih2,
               _Float16* __restrict__ pre_out)
{
    __shared__ char smem[64 * 1024];
    _Float16* X1h  = (_Float16*)smem;                 // [ 0,32K): 64x256 fp16
    half2_t*  Xsh  = (half2_t*)(smem + 32 * 1024);    // [32K,48K): 64x64 half2 (phase B)
    half2_t*  partC = (half2_t*)(smem + 32 * 1024);   // [32K,64K): 64x128 half2 (phase C, aliases Xsh)

    const int tile = blockIdx.x % 1000;
    const int br   = blockIdx.x / 1000;
    const float* Wa = br ? fc21_w : fc11_w;
    const float* ba = br ? fc21_b : fc11_b;
    const float* Wi = br ? W_ih2 : W_ih1;
    const float* bh = br ? b_hh2 : b_hh1;
    const float* bi = br ? b_ih2 : b_ih1;

    const int tid  = threadIdx.x;
    const int row0 = tile * 64;

    // stage X = concat(state, action) as half2 pairs
    const float2* st2 = (const float2*)(state + (size_t)row0 * 96);
    for (int p = tid; p < 64 * 48; p += 256) {
        int r = p / 48, i = p % 48;
        float2 v = st2[r * 48 + i];
        Xsh[r * 64 + i] = half2_t{(_Float16)v.x, (_Float16)v.y};
    }
    const float2* ac2 = (const float2*)(action + (size_t)row0 * 32);
    for (int p = tid; p < 64 * 16; p += 256) {
        int r = p / 16, i = p % 16;
        float2 v = ac2[r * 16 + i];
        Xsh[r * 64 + 48 + i] = half2_t{(_Float16)v.x, (_Float16)v.y};
    }

    const int cp    = tid & 127;        // column pair: cols (2cp, 2cp+1)
    const int c0    = 2 * cp;
    const int rbase = (tid >> 7) * 32;  // wave-uniform row half: 0 or 32

    // ---- phase B weights issued BEFORE the barrier (stay in flight) ----
    half2_t w0[64], w1[64];
#pragma unroll
    for (int i = 0; i < 64; ++i) {
        float2 lo = *(const float2*)(Wa + (size_t)(2 * i) * 256 + c0);
        float2 hi = *(const float2*)(Wa + (size_t)(2 * i + 1) * 256 + c0);
        w0[i] = half2_t{(_Float16)lo.x, (_Float16)hi.x};
        w1[i] = half2_t{(_Float16)lo.y, (_Float16)hi.y};
    }
    const float bA = ba[c0], bB = ba[c0 + 1];

    barrier_lds();                      // Xsh visible; global loads NOT drained

    // ---- phase B: X1 = relu(X @ Wa + ba), K=128, 2 cols/thread ----
#pragma unroll 4
    for (int r = rbase; r < rbase + 32; ++r) {
        const float4* xr = (const float4*)(Xsh + r * 64);
        float s00 = bA, s01 = 0.f, s02 = 0.f, s03 = 0.f;
        float s10 = bB, s11 = 0.f, s12 = 0.f, s13 = 0.f;
#pragma unroll
        for (int k = 0; k < 16; ++k) {
            float4 v = xr[k];                     // 8 halves, wave-broadcast
            const half2_t* hh = (const half2_t*)&v;
            s00 = fdot2(hh[0], w0[4 * k + 0], s00);
            s01 = fdot2(hh[1], w0[4 * k + 1], s01);
            s02 = fdot2(hh[2], w0[4 * k + 2], s02);
            s03 = fdot2(hh[3], w0[4 * k + 3], s03);
            s10 = fdot2(hh[0], w1[4 * k + 0], s10);
            s11 = fdot2(hh[1], w1[4 * k + 1], s11);
            s12 = fdot2(hh[2], w1[4 * k + 2], s12);
            s13 = fdot2(hh[3], w1[4 * k + 3], s13);
        }
        float vA = (s00 + s01) + (s02 + s03); vA = vA > 0.f ? vA : 0.f;
        float vB = (s10 + s11) + (s12 + s13); vB = vB > 0.f ? vB : 0.f;
        ((half2_t*)X1h)[r * 128 + cp] = half2_t{(_Float16)vA, (_Float16)vB};
    }
    barrier_lds();                      // X1h visible; Xsh dead from here on

    // ---- phase C: pre = X1 @ Wi + bias, K=256 as 2 halves of 128 ----
    _Float16* pre = pre_out + (size_t)br * 64000u * 256u;
    const float biasA = bh[c0] + bi[c0];
    const float biasB = bh[c0 + 1] + bi[c0 + 1];

    // K-half 0 -> fp16 partials in partC (aliases Xsh; all waves are past the
    // barrier so no one reads Xsh anymore)
    {
        half2_t u0[64], u1[64];
#pragma unroll
        for (int i = 0; i < 64; ++i) {
            float2 lo = *(const float2*)(Wi + (size_t)(2 * i) * 256 + c0);
            float2 hi = *(const float2*)(Wi + (size_t)(2 * i + 1) * 256 + c0);
            u0[i] = half2_t{(_Float16)lo.x, (_Float16)hi.x};
            u1[i] = half2_t{(_Float16)lo.y, (_Float16)hi.y};
        }
#pragma unroll 4
        for (int r = 0; r < 32; ++r) {
            const int row = rbase + r;
            const float4* xr = (const float4*)(X1h + row * 256);
            float s00 = biasA, s01 = 0.f, s02 = 0.f, s03 = 0.f;
            float s10 = biasB, s11 = 0.f, s12 = 0.f, s13 = 0.f;
#pragma unroll
            for (int k = 0; k < 16; ++k) {
                float4 v = xr[k];
                const half2_t* hh = (const half2_t*)&v;
                s00 = fdot2(hh[0], u0[4 * k + 0], s00);
                s01 = fdot2(hh[1], u0[4 * k + 1], s01);
                s02 = fdot2(hh[2], u0[4 * k + 2], s02);
                s03 = fdot2(hh[3], u0[4 * k + 3], s03);
                s10 = fdot2(hh[0], u1[4 * k + 0], s10);
                s11 = fdot2(hh[1], u1[4 * k + 1], s11);
                s12 = fdot2(hh[2], u1[4 * k + 2], s12);
                s13 = fdot2(hh[3], u1[4 * k + 3], s13);
            }
            partC[row * 128 + cp] = half2_t{(_Float16)((s00 + s01) + (s02 + s03)),
                                            (_Float16)((s10 + s11) + (s12 + s13))};
        }
    }
    // K-half 1: combine (each thread reads only its own partials - no barrier)
    {
        half2_t u0[64], u1[64];
#pragma unroll
        for (int i = 0; i < 64; ++i) {
            float2 lo = *(const float2*)(Wi + (size_t)(128 + 2 * i) * 256 + c0);
            float2 hi = *(const float2*)(Wi + (size_t)(128 + 2 * i + 1) * 256 + c0);
            u0[i] = half2_t{(_Float16)lo.x, (_Float16)hi.x};
            u1[i] = half2_t{(_Float16)lo.y, (_Float16)hi.y};
        }
#pragma unroll 4
        for (int r = 0; r < 32; ++r) {
            const int row = rbase + r;
            const float4* xr = (const float4*)(X1h + row * 256 + 128);
            float s00 = 0.f, s01 = 0.f, s02 = 0.f, s03 = 0.f;
            float s10 = 0.f, s11 = 0.f, s12 = 0.f, s13 = 0.f;
#pragma unroll
            for (int k = 0; k < 16; ++k) {
                float4 v = xr[k];
                const half2_t* hh = (const half2_t*)&v;
                s00 = fdot2(hh[0], u0[4 * k + 0], s00);
                s01 = fdot2(hh[1], u0[4 * k + 1], s01);
                s02 = fdot2(hh[2], u0[4 * k + 2], s02);
                s03 = fdot2(hh[3], u0[4 * k + 3], s03);
                s10 = fdot2(hh[0], u1[4 * k + 0], s10);
                s11 = fdot2(hh[1], u1[4 * k + 1], s11);
                s12 = fdot2(hh[2], u1[4 * k + 2], s12);
                s13 = fdot2(hh[3], u1[4 * k + 3], s13);
            }
            half2_t pp = partC[row * 128 + cp];
            float vA = (float)pp[0] + (s00 + s01) + (s02 + s03);
            float vB = (float)pp[1] + (s10 + s11) + (s12 + s13);
            ((half2_t*)(pre + (size_t)(row0 + row) * 256))[cp] =
                half2_t{(_Float16)vA, (_Float16)vB};
        }
    }
}

// ---------------------------------------------------------------------------
// Kernel 2: recurrence, split-K across 4 waves, 128 blocks (1/CU on 128 CUs).
// Wave w owns k-slice [64w,64w+64); lane owns 4 cols. Partials TRANSPOSED:
// part[parity][col][wave] -> writer: 4 conflict-free b32 writes; reducer:
// ONE ds_read_b128 (single LDS latency on the serial path). barrier_lds()
// keeps the per-step global h-store and pre-prefetch load IN FLIGHT across
// the barrier (no vmcnt(0) drain).
// ---------------------------------------------------------------------------
__global__ __launch_bounds__(256, 1)
void rnn_kernel(const _Float16* __restrict__ pre_all,
                const float* __restrict__ hn,
                const float* __restrict__ W_hh1,
                const float* __restrict__ W_hh2,
                _Float16* __restrict__ h_out)
{
    __shared__ _Float16 hbuf[256];
    __shared__ float part[2][256][4];   // [parity][col][wave] = 8 KB

    const int wg = blockIdx.x;          // 0..127
    const int br = wg >> 6;
    const int b  = wg & 63;
    const float* Whh = br ? W_hh2 : W_hh1;
    const _Float16* pre = pre_all + ((size_t)br * 64000u + (size_t)b * 1000u) * 256u;
    _Float16* hg = h_out + ((size_t)br * 64000u + (size_t)b * 1000u) * 256u;

    const int t  = threadIdx.x;
    const int w  = t >> 6;              // wave id = k-slice
    const int l  = t & 63;
    const int k0 = w * 64;
    const int c0 = l * 4;               // 4 columns per lane

    // weights: cols {c0..c0+3} x k in [k0,k0+64), half2 along k; coalesced f4 loads
    half2_t wh[4][32];
#pragma unroll
    for (int i = 0; i < 32; ++i) {
        float4 lo = *(const float4*)(Whh + (size_t)(k0 + 2 * i) * 256 + c0);
        float4 hi = *(const float4*)(Whh + (size_t)(k0 + 2 * i + 1) * 256 + c0);
        wh[0][i] = half2_t{(_Float16)lo.x, (_Float16)hi.x};
        wh[1][i] = half2_t{(_Float16)lo.y, (_Float16)hi.y};
        wh[2][i] = half2_t{(_Float16)lo.z, (_Float16)hi.z};
        wh[3][i] = half2_t{(_Float16)lo.w, (_Float16)hi.w};
    }

    hbuf[t] = (_Float16)hn[b * 256 + t];
    barrier_lds();

    float pre_c = (float)pre[t];
    float pre_n = (float)pre[256 + t];

    for (int tt = 0; tt < 1000; ++tt) {
        // partial dot over own k-slice, 4 cols
        const float4* hb = (const float4*)&hbuf[k0];
        float s0 = 0.f, s1 = 0.f, s2 = 0.f, s3 = 0.f;
#pragma unroll
        for (int k = 0; k < 8; ++k) {
            float4 v = hb[k];                       // 8 halves, wave-broadcast
            const half2_t* hh = (const half2_t*)&v;
#pragma unroll
            for (int p = 0; p < 4; ++p) {
                s0 = fdot2(hh[p], wh[0][4 * k + p], s0);
                s1 = fdot2(hh[p], wh[1][4 * k + p], s1);
                s2 = fdot2(hh[p], wh[2][4 * k + p], s2);
                s3 = fdot2(hh[p], wh[3][4 * k + p], s3);
            }
        }
        const int pp = tt & 1;
        part[pp][c0 + 0][w] = s0;                   // 4x b32, 2-way-aliased = free
        part[pp][c0 + 1][w] = s1;
        part[pp][c0 + 2][w] = s2;
        part[pp][c0 + 3][w] = s3;
        barrier_lds();                              // publish partials; no vm drain

        // reduce col t: ONE b128 (single LDS latency)
        const float4 pr = *(const float4*)&part[pp][t][0];
        const float z = ((pr.x + pr.y) + (pr.z + pr.w)) + pre_c;
        const float h = 1.0f / (1.0f + __expf(-z));
        const _Float16 h16 = (_Float16)h;
        hbuf[t] = h16;                              // own slice; same-wave consumer
        hg[(size_t)tt * 256 + t] = h16;             // stays in flight across barrier

        const int t2 = (tt + 2 < 1000) ? (tt + 2) : 999;
        pre_c = pre_n;
        pre_n = (float)pre[(size_t)t2 * 256 + t];
    }
}

// ---------------------------------------------------------------------------
// Kernel 3: q head. q[n] = h[n,:] . qw + qb. One thread per output.
// ---------------------------------------------------------------------------
__global__ __launch_bounds__(256, 2)
void q_kernel(const _Float16* __restrict__ h_all,
              const float* __restrict__ fc12_w, const float* __restrict__ fc12_b,
              const float* __restrict__ fc22_w, const float* __restrict__ fc22_b,
              float* __restrict__ out)
{
    const int n  = blockIdx.x * 256 + threadIdx.x;    // 500 blocks -> n < 128000
    const int br = (n >= 64000);                      // block-uniform
    const float* qwp = br ? fc22_w : fc12_w;
    const float  qb  = br ? fc22_b[0] : fc12_b[0];

    half2_t qw[128];
#pragma unroll
    for (int i = 0; i < 128; ++i)
        qw[i] = half2_t{(_Float16)qwp[2 * i], (_Float16)qwp[2 * i + 1]};

    const float4* hr = (const float4*)(h_all + (size_t)n * 256u);
    float s0 = qb, s1 = 0.f, s2 = 0.f, s3 = 0.f;
#pragma unroll
    for (int k = 0; k < 32; ++k) {
        float4 v = hr[k];
        const half2_t* hh = (const half2_t*)&v;
        s0 = fdot2(hh[0], qw[4 * k + 0], s0);
        s1 = fdot2(hh[1], qw[4 * k + 1], s1);
        s2 = fdot2(hh[2], qw[4 * k + 2], s2);
        s3 = fdot2(hh[3], qw[4 * k + 3], s3);
    }
    out[n] = (s0 + s1) + (s2 + s3);
}

// ---------------------------------------------------------------------------
extern "C" void kernel_launch(void* const* d_in, const int* in_sizes, int n_in,
                              void* d_out, int out_size, void* d_ws, size_t ws_size,
                              hipStream_t stream)
{
    const float* state  = (const float*)d_in[0];
    const float* action = (const float*)d_in[1];
    const float* hn     = (const float*)d_in[2];
    const float* fc11_w = (const float*)d_in[3];
    const float* fc11_b = (const float*)d_in[4];
    const float* W_hh1  = (const float*)d_in[5];
    const float* W_ih1  = (const float*)d_in[6];
    const float* b_hh1  = (const float*)d_in[7];
    const float* b_ih1  = (const float*)d_in[8];
    const float* fc12_w = (const float*)d_in[9];
    const float* fc12_b = (const float*)d_in[10];
    const float* fc21_w = (const float*)d_in[11];
    const float* fc21_b = (const float*)d_in[12];
    const float* W_hh2  = (const float*)d_in[13];
    const float* W_ih2  = (const float*)d_in[14];
    const float* b_hh2  = (const float*)d_in[15];
    const float* b_ih2  = (const float*)d_in[16];
    const float* fc22_w = (const float*)d_in[17];
    const float* fc22_b = (const float*)d_in[18];

    _Float16* pre = (_Float16*)d_ws;                // 65.536 MB
    _Float16* hbg = (_Float16*)d_ws + 32768000u;    // +65.536 MB

    ff_kernel<<<2000, 256, 0, stream>>>(state, action,
                                        fc11_w, fc11_b, W_ih1, b_hh1, b_ih1,
                                        fc21_w, fc21_b, W_ih2, b_hh2, b_ih2,
                                        pre);
    rnn_kernel<<<128, 256, 0, stream>>>(pre, hn, W_hh1, W_hh2, hbg);
    q_kernel<<<500, 256, 0, stream>>>(hbg, fc12_w, fc12_b, fc22_w, fc22_b,
                                      (float*)d_out);
}

// Round 6
// 803.834 us; speedup vs baseline: 1.5109x; 1.3635x over previous
//
#include <hip/hip_runtime.h>
#include <math.h>

// B=64, T=1000, S=96, A=32, INP=128, H=256. All I/O fp32.
// d_ws: pre fp16 [2][64000][256] = 65,536,000 B | h fp16 same = 65,536,000 B.
// W frag tables (393,216 B) live in the TAIL of the h region: ff reads them
// before rnn overwrites that region with h. Total ws use = 131,072,000 B.

typedef _Float16 half2_t __attribute__((ext_vector_type(2)));
typedef __attribute__((ext_vector_type(8))) short bf16x8;   // 8 bf16 in 4 VGPRs
typedef __attribute__((ext_vector_type(4))) float f32x4;

__device__ __forceinline__ float fdot2(half2_t a, half2_t b, float c) {
#if __has_builtin(__builtin_amdgcn_fdot2)
    return __builtin_amdgcn_fdot2(a, b, c, false);   // v_dot2_f32_f16
#else
    return c + (float)a[0] * (float)b[0] + (float)a[1] * (float)b[1];
#endif
}

__device__ __forceinline__ short f2bf(float f) {     // fp32 -> bf16 (RNE)
    unsigned u = __builtin_bit_cast(unsigned, f);
    return (short)((u + 0x7FFFu + ((u >> 16) & 1u)) >> 16);
}

// Barrier WITHOUT the vmcnt(0) drain __syncthreads() inserts. Safe when
// inter-wave communication is LDS-only (lgkmcnt covers DS ops).
__device__ __forceinline__ void barrier_lds() {
    __asm__ __volatile__("s_waitcnt lgkmcnt(0)" ::: "memory");
    __builtin_amdgcn_s_barrier();
}

// ---------------------------------------------------------------------------
// Kernel 0: pre-swizzle W into MFMA B-fragment tables (bf16).
// B-frag for mfma_f32_16x16x32_bf16: lane holds B[k = (lane>>4)*8 + j][n = lane&15]
// G1 entries: ((br*16+nt)*4+ks)*64+lane   (Wa: fc11_w/fc21_w, K=128)
// G2 entries: 8192 + ((br*16+nt)*8+ks)*64+lane (Wi: W_ih1/W_ih2, K=256)
// ---------------------------------------------------------------------------
__global__ __launch_bounds__(256, 1)
void prep_kernel(const float* __restrict__ fc11_w, const float* __restrict__ W_ih1,
                 const float* __restrict__ fc21_w, const float* __restrict__ W_ih2,
                 short* __restrict__ tab)
{
    const int e    = blockIdx.x * 256 + threadIdx.x;   // 96*256 = 24576 entries
    const int lane = e & 63;
    const int q = lane >> 4, m = lane & 15;
    const float* W;
    int k0, n;
    if (e < 8192) {                       // G1
        int t_ = e >> 6;
        int ks = t_ & 3, nt = (t_ >> 2) & 15, br = t_ >> 6;
        W = br ? fc21_w : fc11_w;
        k0 = ks * 32 + q * 8; n = nt * 16 + m;
    } else {                              // G2
        int t_ = (e - 8192) >> 6;
        int ks = t_ & 7, nt = (t_ >> 3) & 15, br = t_ >> 7;
        W = br ? W_ih2 : W_ih1;
        k0 = ks * 32 + q * 8; n = nt * 16 + m;
    }
    bf16x8 v;
#pragma unroll
    for (int j = 0; j < 8; ++j) v[j] = f2bf(W[(size_t)(k0 + j) * 256 + n]);
    ((bf16x8*)tab)[e] = v;
}

// ---------------------------------------------------------------------------
// Kernel 1: feed-forward via MFMA. Block = 64 rows; wave w owns rows
// [row0+16w, +16). GEMM1 (K=128): a-frags straight from global state/action
// (k-segments never straddle the 96 boundary since 96 % 8 == 0). relu+bias ->
// bf16 X1 in LDS (row stride 264 = conflict-free frag reads). GEMM2 (K=256):
// a-frags from LDS (same-wave dependency -> no barrier anywhere). B-frags for
// both GEMMs from the L2-resident prep tables.
// ---------------------------------------------------------------------------
__global__ __launch_bounds__(256, 2)
void ff_kernel(const float* __restrict__ state,
               const float* __restrict__ action,
               const float* __restrict__ fc11_b, const float* __restrict__ fc21_b,
               const float* __restrict__ b_hh1, const float* __restrict__ b_ih1,
               const float* __restrict__ b_hh2, const float* __restrict__ b_ih2,
               const short* __restrict__ tab,
               _Float16* __restrict__ pre_out)
{
    __shared__ short X1[64 * 264];        // 33.8 KB bf16, +8 pad per row

    const int tile = blockIdx.x % 1000;
    const int br   = blockIdx.x / 1000;
    const int tid  = threadIdx.x;
    const int w    = tid >> 6;
    const int lane = tid & 63;
    const int q = lane >> 4, m = lane & 15;
    const int row0 = tile * 64;
    const int rw   = row0 + 16 * w + m;   // a-frag row of this lane

    const float* ba = br ? fc21_b : fc11_b;
    const float* bh = br ? b_hh2 : b_hh1;
    const float* bi = br ? b_ih2 : b_ih1;
    const bf16x8* tG1 = (const bf16x8*)tab + (size_t)br * 4096;
    const bf16x8* tG2 = (const bf16x8*)tab + 8192 + (size_t)br * 8192;

    // per-lane bias values (col = nt*16 + m)
    float ba_v[16], bb_v[16];
#pragma unroll
    for (int nt = 0; nt < 16; ++nt) {
        int c = nt * 16 + m;
        ba_v[nt] = ba[c];
        bb_v[nt] = bh[c] + bi[c];
    }

    // GEMM1 a-frags from global X = concat(state[96], action[32])
    bf16x8 af[4];
#pragma unroll
    for (int ks = 0; ks < 4; ++ks) {
        int k0 = ks * 32 + q * 8;
        const float* src = (k0 < 96) ? (state  + (size_t)rw * 96 + k0)
                                     : (action + (size_t)rw * 32 + (k0 - 96));
        float4 x0 = *(const float4*)src;
        float4 x1 = *(const float4*)(src + 4);
        bf16x8 a;
        a[0] = f2bf(x0.x); a[1] = f2bf(x0.y); a[2] = f2bf(x0.z); a[3] = f2bf(x0.w);
        a[4] = f2bf(x1.x); a[5] = f2bf(x1.y); a[6] = f2bf(x1.z); a[7] = f2bf(x1.w);
        af[ks] = a;
    }

    // GEMM1: X1 = relu(X @ Wa + ba)
#pragma unroll
    for (int nt = 0; nt < 16; ++nt) {
        f32x4 acc = {0.f, 0.f, 0.f, 0.f};
#pragma unroll
        for (int ks = 0; ks < 4; ++ks)
            acc = __builtin_amdgcn_mfma_f32_16x16x32_bf16(
                      af[ks], tG1[(nt * 4 + ks) * 64 + lane], acc, 0, 0, 0);
#pragma unroll
        for (int r = 0; r < 4; ++r) {     // D: col=lane&15, row=q*4+r
            float v = acc[r] + ba_v[nt];
            v = v > 0.f ? v : 0.f;
            X1[(16 * w + q * 4 + r) * 264 + nt * 16 + m] = f2bf(v);
        }
    }
    // X1 rows [16w,16w+16) written and read by THIS wave only -> lgkmcnt
    // ordering suffices; no barrier.

    // GEMM2 a-frags from LDS
    bf16x8 a2[8];
#pragma unroll
    for (int ks = 0; ks < 8; ++ks)
        a2[ks] = *(const bf16x8*)&X1[(16 * w + m) * 264 + ks * 32 + q * 8];

    _Float16* pre = pre_out + (size_t)br * 64000u * 256u;
#pragma unroll
    for (int nt = 0; nt < 16; ++nt) {
        f32x4 acc = {0.f, 0.f, 0.f, 0.f};
#pragma unroll
        for (int ks = 0; ks < 8; ++ks)
            acc = __builtin_amdgcn_mfma_f32_16x16x32_bf16(
                      a2[ks], tG2[(nt * 8 + ks) * 64 + lane], acc, 0, 0, 0);
#pragma unroll
        for (int r = 0; r < 4; ++r) {
            float v = acc[r] + bb_v[nt];
            pre[(size_t)(row0 + 16 * w + q * 4 + r) * 256 + nt * 16 + m] = (_Float16)v;
        }
    }
}

// ---------------------------------------------------------------------------
// Kernel 2: recurrence, split-K across 4 waves, 128 blocks. Partials in
// part[parity][wave][col]: writer = one b128 at consecutive 16 B/lane
// (conflict-free), reader = 4 b32 at consecutive dwords (conflict-free).
// ONE barrier_lds()/step (wave w finalizes exactly the h-slice it reads).
// 8 accumulators -> fdot2 dep-chain depth 16.
// ---------------------------------------------------------------------------
__global__ __launch_bounds__(256, 1)
void rnn_kernel(const _Float16* __restrict__ pre_all,
                const float* __restrict__ hn,
                const float* __restrict__ W_hh1,
                const float* __restrict__ W_hh2,
                _Float16* __restrict__ h_out)
{
    __shared__ _Float16 hbuf[256];
    __shared__ float part[2][4][256];   // [parity][wave][col] = 8 KB

    const int wg = blockIdx.x;          // 0..127
    const int br = wg >> 6;
    const int b  = wg & 63;
    const float* Whh = br ? W_hh2 : W_hh1;
    const _Float16* pre = pre_all + ((size_t)br * 64000u + (size_t)b * 1000u) * 256u;
    _Float16* hg = h_out + ((size_t)br * 64000u + (size_t)b * 1000u) * 256u;

    const int t  = threadIdx.x;
    const int w  = t >> 6;              // wave id = k-slice
    const int l  = t & 63;
    const int k0 = w * 64;
    const int c0 = l * 4;               // 4 columns per lane

    // weights: cols {c0..c0+3} x k in [k0,k0+64), half2 along k
    half2_t wh[4][32];
#pragma unroll
    for (int i = 0; i < 32; ++i) {
        float4 lo = *(const float4*)(Whh + (size_t)(k0 + 2 * i) * 256 + c0);
        float4 hi = *(const float4*)(Whh + (size_t)(k0 + 2 * i + 1) * 256 + c0);
        wh[0][i] = half2_t{(_Float16)lo.x, (_Float16)hi.x};
        wh[1][i] = half2_t{(_Float16)lo.y, (_Float16)hi.y};
        wh[2][i] = half2_t{(_Float16)lo.z, (_Float16)hi.z};
        wh[3][i] = half2_t{(_Float16)lo.w, (_Float16)hi.w};
    }

    hbuf[t] = (_Float16)hn[b * 256 + t];
    barrier_lds();

    float pre_c = (float)pre[t];
    float pre_n = (float)pre[256 + t];

    for (int tt = 0; tt < 1000; ++tt) {
        // issue t+2 prefetch early; stays in flight across the barrier
        const int t2 = (tt + 2 < 1000) ? (tt + 2) : 999;
        const float pre_n2 = (float)pre[(size_t)t2 * 256 + t];

        // partial dot over own k-slice, 4 cols, 2 accumulators each
        const float4* hb = (const float4*)&hbuf[k0];
        float sA0 = 0.f, sA1 = 0.f, sA2 = 0.f, sA3 = 0.f;
        float sB0 = 0.f, sB1 = 0.f, sB2 = 0.f, sB3 = 0.f;
#pragma unroll
        for (int k = 0; k < 8; ++k) {
            float4 v = hb[k];                       // 8 halves, wave-broadcast
            const half2_t* hh = (const half2_t*)&v;
            sA0 = fdot2(hh[0], wh[0][4 * k + 0], sA0);
            sA1 = fdot2(hh[0], wh[1][4 * k + 0], sA1);
            sA2 = fdot2(hh[0], wh[2][4 * k + 0], sA2);
            sA3 = fdot2(hh[0], wh[3][4 * k + 0], sA3);
            sA0 = fdot2(hh[1], wh[0][4 * k + 1], sA0);
            sA1 = fdot2(hh[1], wh[1][4 * k + 1], sA1);
            sA2 = fdot2(hh[1], wh[2][4 * k + 1], sA2);
            sA3 = fdot2(hh[1], wh[3][4 * k + 1], sA3);
            sB0 = fdot2(hh[2], wh[0][4 * k + 2], sB0);
            sB1 = fdot2(hh[2], wh[1][4 * k + 2], sB1);
            sB2 = fdot2(hh[2], wh[2][4 * k + 2], sB2);
            sB3 = fdot2(hh[2], wh[3][4 * k + 2], sB3);
            sB0 = fdot2(hh[3], wh[0][4 * k + 3], sB0);
            sB1 = fdot2(hh[3], wh[1][4 * k + 3], sB1);
            sB2 = fdot2(hh[3], wh[2][4 * k + 3], sB2);
            sB3 = fdot2(hh[3], wh[3][4 * k + 3], sB3);
        }
        const int pp = tt & 1;
        *(float4*)&part[pp][w][c0] =
            float4{sA0 + sB0, sA1 + sB1, sA2 + sB2, sA3 + sB3};
        barrier_lds();                              // publish partials

        // reduce col t (wave w owns its own next-step slice)
        const float z = ((part[pp][0][t] + part[pp][1][t]) +
                         (part[pp][2][t] + part[pp][3][t])) + pre_c;
        const float h = 1.0f / (1.0f + __expf(-z));
        const _Float16 h16 = (_Float16)h;
        hbuf[t] = h16;                              // same-wave consumer
        hg[(size_t)tt * 256 + t] = h16;             // in flight across barrier

        pre_c = pre_n;
        pre_n = pre_n2;
    }
}

// ---------------------------------------------------------------------------
// Kernel 3: q head. q[n] = h[n,:] . qw + qb. One thread per output.
// ---------------------------------------------------------------------------
__global__ __launch_bounds__(256, 2)
void q_kernel(const _Float16* __restrict__ h_all,
              const float* __restrict__ fc12_w, const float* __restrict__ fc12_b,
              const float* __restrict__ fc22_w, const float* __restrict__ fc22_b,
              float* __restrict__ out)
{
    const int n  = blockIdx.x * 256 + threadIdx.x;    // 500 blocks -> n < 128000
    const int br = (n >= 64000);                      // block-uniform
    const float* qwp = br ? fc22_w : fc12_w;
    const float  qb  = br ? fc22_b[0] : fc12_b[0];

    half2_t qw[128];
#pragma unroll
    for (int i = 0; i < 128; ++i)
        qw[i] = half2_t{(_Float16)qwp[2 * i], (_Float16)qwp[2 * i + 1]};

    const float4* hr = (const float4*)(h_all + (size_t)n * 256u);
    float s0 = qb, s1 = 0.f, s2 = 0.f, s3 = 0.f;
#pragma unroll
    for (int k = 0; k < 32; ++k) {
        float4 v = hr[k];
        const half2_t* hh = (const half2_t*)&v;
        s0 = fdot2(hh[0], qw[4 * k + 0], s0);
        s1 = fdot2(hh[1], qw[4 * k + 1], s1);
        s2 = fdot2(hh[2], qw[4 * k + 2], s2);
        s3 = fdot2(hh[3], qw[4 * k + 3], s3);
    }
    out[n] = (s0 + s1) + (s2 + s3);
}

// ---------------------------------------------------------------------------
extern "C" void kernel_launch(void* const* d_in, const int* in_sizes, int n_in,
                              void* d_out, int out_size, void* d_ws, size_t ws_size,
                              hipStream_t stream)
{
    const float* state  = (const float*)d_in[0];
    const float* action = (const float*)d_in[1];
    const float* hn     = (const float*)d_in[2];
    const float* fc11_w = (const float*)d_in[3];
    const float* fc11_b = (const float*)d_in[4];
    const float* W_hh1  = (const float*)d_in[5];
    const float* W_ih1  = (const float*)d_in[6];
    const float* b_hh1  = (const float*)d_in[7];
    const float* b_ih1  = (const float*)d_in[8];
    const float* fc12_w = (const float*)d_in[9];
    const float* fc12_b = (const float*)d_in[10];
    const float* fc21_w = (const float*)d_in[11];
    const float* fc21_b = (const float*)d_in[12];
    const float* W_hh2  = (const float*)d_in[13];
    const float* W_ih2  = (const float*)d_in[14];
    const float* b_hh2  = (const float*)d_in[15];
    const float* b_ih2  = (const float*)d_in[16];
    const float* fc22_w = (const float*)d_in[17];
    const float* fc22_b = (const float*)d_in[18];

    _Float16* pre = (_Float16*)d_ws;                         // 65,536,000 B
    _Float16* hbg = (_Float16*)d_ws + 32768000u;             // 65,536,000 B
    // frag tables in the tail of the h region (dead until rnn runs; ff is done
    // by then): 131,072,000 - 393,216 = 130,678,784 (16 B aligned)
    short* tab = (short*)((char*)d_ws + 130678784u);

    prep_kernel<<<96, 256, 0, stream>>>(fc11_w, W_ih1, fc21_w, W_ih2, tab);
    ff_kernel<<<2000, 256, 0, stream>>>(state, action,
                                        fc11_b, fc21_b, b_hh1, b_ih1,
                                        b_hh2, b_ih2, tab, pre);
    rnn_kernel<<<128, 256, 0, stream>>>(pre, hn, W_hh1, W_hh2, hbg);
    q_kernel<<<500, 256, 0, stream>>>(hbg, fc12_w, fc12_b, fc22_w, fc22_b,
                                      (float*)d_out);
}